// Round 3
// baseline (330.013 us; speedup 1.0000x reference)
//
#include <hip/hip_runtime.h>
#include <math.h>
#include <stdint.h>

#define NTOT   8192
#define HALF_N 4096
#define DIM    512
#define INV_T  14.2857142857142857f   // 1/0.07

using s16x8 = __attribute__((ext_vector_type(8))) short;
using f32x4 = __attribute__((ext_vector_type(4))) float;

// Scratch in static device globals (fully rewritten every call; no d_ws use).
__device__ unsigned short g_fnb[NTOT * DIM];   // normalized bf16 matrix, 8 MB
__device__ float g_pos[NTOT];
__device__ float g_sumexp[NTOT];
__device__ int   g_cnt[NTOT];

__device__ __forceinline__ float bf2f(unsigned short u) {
  union { unsigned int i; float f; } v; v.i = ((unsigned int)u) << 16; return v.f;
}
__device__ __forceinline__ unsigned short f2bf(float x) {
  union { float f; unsigned int i; } v; v.f = x;
  unsigned int u = v.i;
  return (unsigned short)((u + 0x7FFFu + ((u >> 16) & 1u)) >> 16);
}

// async global->LDS, 16 B per lane. LDS dest must be wave-uniform base + lane*16
// (our layout satisfies this exactly — see staging map in kmain).
__device__ __forceinline__ void async_copy16(void* lds, const void* g) {
  __builtin_amdgcn_global_load_lds(
      (const __attribute__((address_space(1))) unsigned int*)g,
      (__attribute__((address_space(3))) unsigned int*)lds, 16, 0, 0);
}

// ---------------- kernel 1: normalize rows -> bf16; zero the stats ----------------
__global__ __launch_bounds__(256) void knorm(const float* __restrict__ f1,
                                             const float* __restrict__ f2) {
  const int gid = blockIdx.x * 256 + threadIdx.x;
  if (gid < NTOT) { g_sumexp[gid] = 0.f; g_cnt[gid] = 0; }

  const int row  = blockIdx.x * 4 + (threadIdx.x >> 6);
  const int lane = threadIdx.x & 63;
  const float* src = (row < HALF_N) ? (f1 + (size_t)row * DIM)
                                    : (f2 + (size_t)(row - HALF_N) * DIM);
  float4 v0 = ((const float4*)src)[lane];
  float4 v1 = ((const float4*)src)[lane + 64];
  float ss = v0.x*v0.x + v0.y*v0.y + v0.z*v0.z + v0.w*v0.w
           + v1.x*v1.x + v1.y*v1.y + v1.z*v1.z + v1.w*v1.w;
  #pragma unroll
  for (int o = 32; o >= 1; o >>= 1) ss += __shfl_xor(ss, o, 64);
  const float sc = 1.0f / fmaxf(sqrtf(ss), 1e-8f);
  ushort4 h0, h1;
  h0.x = f2bf(v0.x * sc); h0.y = f2bf(v0.y * sc);
  h0.z = f2bf(v0.z * sc); h0.w = f2bf(v0.w * sc);
  h1.x = f2bf(v1.x * sc); h1.y = f2bf(v1.y * sc);
  h1.z = f2bf(v1.z * sc); h1.w = f2bf(v1.w * sc);
  ushort4* dst = (ushort4*)(g_fnb + (size_t)row * DIM);
  dst[lane]      = h0;
  dst[lane + 64] = h1;
}

// ---------------- kernel 2: pos[i] = <fn_i, fn_{i^4096}> (bf16 inputs, fp32 acc)
__global__ __launch_bounds__(256) void kpos() {
  const int i    = blockIdx.x * 4 + (threadIdx.x >> 6);
  const int lane = threadIdx.x & 63;
  const ushort4* a = (const ushort4*)(g_fnb + (size_t)i * DIM);
  const ushort4* b = (const ushort4*)(g_fnb + (size_t)(i ^ HALF_N) * DIM);
  float s = 0.f;
  #pragma unroll
  for (int t = 0; t < 2; ++t) {
    ushort4 ua = a[lane + t * 64];
    ushort4 ub = b[lane + t * 64];
    s += bf2f(ua.x)*bf2f(ub.x) + bf2f(ua.y)*bf2f(ub.y)
       + bf2f(ua.z)*bf2f(ub.z) + bf2f(ua.w)*bf2f(ub.w);
  }
  #pragma unroll
  for (int o = 32; o >= 1; o >>= 1) s += __shfl_xor(s, o, 64);
  if (lane == 0) g_pos[i] = s;
}

// ---------------- kernel 3: fused GEMM + row reductions (m97 structure) ----------------
// grid 64x64: one 128x128 output tile per block. 4 waves, wave tile 64x64
// (4x4 frags of 16x16x32 bf16 MFMA). BK=64, global_load_lds staging,
// XOR-swizzled LDS layout (col_block ^= row&7) -> conflict-free ds_read_b128.
__global__ __launch_bounds__(256, 3) void kmain() {
  __shared__ unsigned short As[128 * 64];
  __shared__ unsigned short Bs[128 * 64];

  const int tid  = threadIdx.x;
  const int lane = tid & 63;
  const int w    = tid >> 6;
  const int bi   = blockIdx.x >> 6;
  const int bj   = blockIdx.x & 63;
  const int i0   = bi * 128;
  const int j0   = bj * 128;

  const int wr   = (w >> 1) * 64;   // wave row base within 128-tile
  const int wc   = (w & 1) * 64;    // wave col base
  const int lrow = lane & 15;
  const int lq   = lane >> 4;

  // staging map: per call a wave covers 8 rows x 64 cols.
  // lane l -> row w*32 + c*8 + (l>>3), physical col block (l&7).
  // XOR swizzle: physical block (l&7) holds logical block (l&7)^(l>>3),
  // so LDS byte offset = wave_base + l*16 (contiguous, as global_load_lds needs).
  const int sr = lane >> 3;
  const int lb = (lane & 7) ^ sr;   // logical col block fetched by this lane

  const unsigned short* Ag = g_fnb + (size_t)(i0 + w * 32 + sr) * DIM + lb * 8;
  const unsigned short* Bg = g_fnb + (size_t)(j0 + w * 32 + sr) * DIM + lb * 8;
  unsigned short* Al = &As[(w * 32 + sr) * 64 + (lane & 7) * 8];
  unsigned short* Bl = &Bs[(w * 32 + sr) * 64 + (lane & 7) * 8];

  f32x4 acc[4][4];
  #pragma unroll
  for (int a = 0; a < 4; ++a)
    #pragma unroll
    for (int b = 0; b < 4; ++b) { acc[a][b][0]=0.f; acc[a][b][1]=0.f; acc[a][b][2]=0.f; acc[a][b][3]=0.f; }

  for (int kt = 0; kt < 8; ++kt) {
    __syncthreads();                      // previous-iter LDS reads done
    const int kb = kt * 64;
    #pragma unroll
    for (int c = 0; c < 4; ++c) {
      async_copy16(Al + c * 8 * 64, Ag + (size_t)c * 8 * DIM + kb);
      async_copy16(Bl + c * 8 * 64, Bg + (size_t)c * 8 * DIM + kb);
    }
    __syncthreads();                      // staging complete (vmcnt(0) drain)

    #pragma unroll
    for (int kk = 0; kk < 2; ++kk) {
      s16x8 af[4], bf[4];
      #pragma unroll
      for (int mi = 0; mi < 4; ++mi) {
        const int r = wr + mi * 16 + lrow;
        af[mi] = *(const s16x8*)(&As[r * 64 + (((kk * 4 + lq) ^ (lrow & 7)) * 8)]);
      }
      #pragma unroll
      for (int ni = 0; ni < 4; ++ni) {
        const int r = wc + ni * 16 + lrow;
        bf[ni] = *(const s16x8*)(&Bs[r * 64 + (((kk * 4 + lq) ^ (lrow & 7)) * 8)]);
      }
      #pragma unroll
      for (int mi = 0; mi < 4; ++mi)
        #pragma unroll
        for (int ni = 0; ni < 4; ++ni)
          acc[mi][ni] = __builtin_amdgcn_mfma_f32_16x16x32_bf16(af[mi], bf[ni], acc[mi][ni], 0, 0, 0);
    }
  }

  // epilogue: per-row exp-sum + rank count for this 128-col slab, then atomics.
  // C layout: col = lane&15, row = lq*4 + reg (verified m89/m91).
  #pragma unroll
  for (int mi = 0; mi < 4; ++mi) {
    #pragma unroll
    for (int r = 0; r < 4; ++r) {
      const int i  = i0 + wr + mi * 16 + lq * 4 + r;
      const float pv = g_pos[i];
      float s = 0.f; int c = 0;
      #pragma unroll
      for (int ni = 0; ni < 4; ++ni) {
        const int j = j0 + wc + ni * 16 + lrow;
        const float v = acc[mi][ni][r];
        const float e = __expf(v * INV_T);
        const bool diag = (j == i);
        s += diag ? 0.f : e;
        c += (!diag && (j != (i ^ HALF_N)) && (v > pv)) ? 1 : 0;
      }
      #pragma unroll
      for (int o = 1; o < 16; o <<= 1) {
        s += __shfl_xor(s, o, 64);
        c += __shfl_xor(c, o, 64);
      }
      if (lrow == 0) {
        atomicAdd(&g_sumexp[i], s);
        atomicAdd(&g_cnt[i], c);
      }
    }
  }
}

// ---------------- kernel 4: finalize the 4 scalars ----------------
__global__ __launch_bounds__(256) void kfin(float* __restrict__ out) {
  const int tid = threadIdx.x;
  float nll = 0.f, t1 = 0.f, t5 = 0.f, mr = 0.f;
  for (int i = tid; i < NTOT; i += 256) {
    nll += -g_pos[i] * INV_T + logf(g_sumexp[i]);
    const int c = g_cnt[i];
    t1 += (c == 0) ? 1.f : 0.f;
    t5 += (c < 5) ? 1.f : 0.f;
    mr += (float)c;
  }
  #pragma unroll
  for (int o = 32; o >= 1; o >>= 1) {
    nll += __shfl_xor(nll, o, 64);
    t1  += __shfl_xor(t1, o, 64);
    t5  += __shfl_xor(t5, o, 64);
    mr  += __shfl_xor(mr, o, 64);
  }
  __shared__ float red[4][4];
  const int wv = tid >> 6, lane = tid & 63;
  if (lane == 0) { red[wv][0] = nll; red[wv][1] = t1; red[wv][2] = t5; red[wv][3] = mr; }
  __syncthreads();
  if (tid == 0) {
    float a = 0.f, b = 0.f, c = 0.f, d = 0.f;
    for (int k = 0; k < 4; ++k) { a += red[k][0]; b += red[k][1]; c += red[k][2]; d += red[k][3]; }
    out[0] = a / (float)NTOT;
    out[1] = b / (float)NTOT;
    out[2] = c / (float)NTOT;
    out[3] = 1.f + d / (float)NTOT;
  }
}

extern "C" void kernel_launch(void* const* d_in, const int* in_sizes, int n_in,
                              void* d_out, int out_size, void* d_ws, size_t ws_size,
                              hipStream_t stream) {
  const float* f1 = (const float*)d_in[0];
  const float* f2 = (const float*)d_in[1];
  float* out = (float*)d_out;

  knorm<<<dim3(2048), dim3(256), 0, stream>>>(f1, f2);
  kpos <<<dim3(2048), dim3(256), 0, stream>>>();
  kmain<<<dim3(4096), dim3(256), 0, stream>>>();
  kfin <<<dim3(1),    dim3(256), 0, stream>>>(out);
}